// Round 1
// baseline (10094.041 us; speedup 1.0000x reference)
//
#include <hip/hip_runtime.h>

// BRITS-style recurrent imputation on MI355X.
// Partition: 256 blocks = 8 batch-tiles(16 rows) x 32 H-chunks(16 H each).
// Weights pre-packed to f16 MFMA B-fragments, persistent in VGPRs.
// Per-step cross-block h exchange via device-scope flag counters (per batch-tile).
// gamma_h(t+1) folded into producer's h store. deltas/masks/msum precomputed.

#define B_ 128
#define T_ 256
#define D_ 128
#define H_ 512

typedef _Float16 f16x8 __attribute__((ext_vector_type(8)));
typedef float    f32x4 __attribute__((ext_vector_type(4)));

// ---- workspace layout (bytes) ----
#define OFF_HBUF   0u          // f16 [2][128][512]        262144
#define OFF_CNT    262144u     // uint [256][8]            8192
#define OFF_MSUM   270336u     // float [256]              1024
#define OFF_BG     271360u     // float [2048]             8192
#define OFF_WH     279552u     // f16 [8][16][64][8]       131072
#define OFF_WF     410624u     // f16 [8][4][64][8]        32768
#define OFF_WD     443392u     // f16 [32][4][64][8]       131072
#define OFF_GB     574464u     // f16 [32][4][24][64][8]   3145728
#define OFF_MBF    3720192u    // f16 [128][256][128]      8388608
#define OFF_DBF    12108800u   // f16 [128][256][128]      8388608
// total 20497408 bytes (~19.6 MB) of d_ws

__device__ __forceinline__ float sigm(float x)  { return __fdividef(1.0f, 1.0f + __expf(-x)); }
__device__ __forceinline__ float tanh_(float x) { return 1.0f - __fdividef(2.0f, __expf(2.0f*x) + 1.0f); }

// ---------------- pre-kernels ----------------

__global__ void k_zero(unsigned int* __restrict__ wsu, float* __restrict__ out){
  int id = blockIdx.x*256 + threadIdx.x;
  if (id < 67840) wsu[id] = 0u;     // hbuf + cnt + msum
  if (id == 0) out[0] = 0.0f;
}

// masks (f16) + msum[t]
__global__ void k_mask(const float* __restrict__ data, _Float16* __restrict__ mbf,
                       float* __restrict__ msum){
  int idx = blockIdx.x*256 + threadIdx.x;     // < 128*256*128
  float v = data[idx];
  bool m = (v == v);
  mbf[idx] = m ? (_Float16)1.0f : (_Float16)0.0f;
  unsigned long long bal = __ballot(m);       // 64 lanes share one (b,t) row half
  if ((threadIdx.x & 63) == 0) {
    int t = (idx >> 7) & 255;
    atomicAdd(&msum[t], (float)__popcll(bal));
  }
}

// delta_calc: per (b,t) sequential scan over d (exact reference semantics)
__global__ void k_delta(const float* __restrict__ data, _Float16* __restrict__ dbf){
  int gid = blockIdx.x*64 + threadIdx.x;      // 32768 = B*T
  int b = gid >> 8, t = gid & 255;
  _Float16* orow = dbf + (size_t)(b*256 + t)*128;
  if (t == 0) {
    f16x8 z;
    #pragma unroll
    for (int i=0;i<8;i++) z[i] = (_Float16)0.0f;
    #pragma unroll
    for (int k=0;k<16;k++) ((f16x8*)orow)[k] = z;
    return;
  }
  const float* rp = data + (size_t)(b*256 + (t-1))*128;
  const float* rt = data + (size_t)(b*256 + t)*128;
  unsigned long long mp0=0, mp1=0, mt0=0, mt1=0;
  for (int d=0; d<64; ++d) {
    if (rp[d]==rp[d])       mp0 |= (1ull<<d);
    if (rp[64+d]==rp[64+d]) mp1 |= (1ull<<d);
    if (rt[d]==rt[d])       mt0 |= (1ull<<d);
    if (rt[64+d]==rt[64+d]) mt1 |= (1ull<<d);
  }
  float carry = 0.0f;
  for (int g=0; g<16; ++g) {
    f16x8 v;
    #pragma unroll
    for (int j=0; j<8; ++j) {
      int d = g*8 + j;
      bool prevm = (d<64)   ? ((mp0>>d)&1ull)       : ((mp1>>(d-64))&1ull);
      int dm1 = (d-1)&127;
      bool leftm = (dm1<64) ? ((mt0>>dm1)&1ull)     : ((mt1>>(dm1-64))&1ull);
      float val = (!prevm) ? (carry+1.0f) : (leftm ? 1.0f : 0.0f);
      carry = val;
      v[j] = (_Float16)val;
    }
    ((f16x8*)orow)[g] = v;
  }
}

// Weight pre-pack into MFMA B-fragment order: [..][ks][lane][8], B[k][n]=W[n][k],
// n = lane&15, k = ks*32 + (lane>>4)*8 + j.
__global__ void k_pack_wh(const float* __restrict__ Wh, _Float16* __restrict__ dst){
  int id = blockIdx.x*256 + threadIdx.x;      // 65536 = [8][16][64][8]
  int j = id & 7, l = (id>>3)&63, ks = (id>>9)&15, nt = id>>13;
  int row = nt*16 + (l&15);
  int k   = ks*32 + ((l>>4)&3)*8 + j;
  dst[id] = (_Float16)Wh[row*512 + k];
}
__global__ void k_pack_wf(const float* __restrict__ Wf, _Float16* __restrict__ dst){
  int id = blockIdx.x*256 + threadIdx.x;      // 16384 = [8][4][64][8]
  int j = id & 7, l = (id>>3)&63, ks = (id>>9)&3, nt = id>>11;
  int row = nt*16 + (l&15);
  int k   = ks*32 + ((l>>4)&3)*8 + j;
  float v = (row == k) ? 0.0f : Wf[row*128 + k];   // off-diagonal mask
  dst[id] = (_Float16)v;
}
__global__ void k_pack_wd(const float* __restrict__ Wdh, _Float16* __restrict__ dst){
  int id = blockIdx.x*256 + threadIdx.x;      // 65536 = [32][4][64][8]
  int j = id & 7, l = (id>>3)&63, ks = (id>>9)&3, c = id>>11;
  int row = c*16 + (l&15);
  int k   = ks*32 + ((l>>4)&3)*8 + j;
  dst[id] = (_Float16)Wdh[row*128 + k];
}
__global__ void k_pack_gb(const float* __restrict__ W_ih, const float* __restrict__ W_hh,
                          _Float16* __restrict__ dst){
  int id = blockIdx.x*256 + threadIdx.x;      // 1572864 = [32][4][24][64][8]
  int j = id & 7, l = (id>>3)&63;
  int f = id>>9;
  int ks = f % 24; f /= 24;
  int g = f & 3, c = f >> 2;
  int rn = g*512 + c*16 + (l&15);
  int k  = ks*32 + ((l>>4)&3)*8 + j;          // inp K: [0,256)=[c_c,m], [256,768)=h
  float v = (k < 256) ? W_ih[rn*256 + k] : W_hh[rn*512 + (k-256)];
  dst[id] = (_Float16)v;
}
__global__ void k_pack_bias(const float* __restrict__ b_ih, const float* __restrict__ b_hh,
                            float* __restrict__ dst){
  int id = blockIdx.x*256 + threadIdx.x;      // 2048
  dst[id] = b_ih[id] + b_hh[id];
}

// ---------------- main persistent kernel ----------------
// grid 256 blocks (8 batch-tiles x 32 chunks), 256 threads (4 waves, 1/SIMD).
// VGPR-resident weight frags (~270/lane) force 1 block/CU -> all co-resident.

__global__ __launch_bounds__(256, 1) void brits_main(
    const float* __restrict__ data,
    const float* __restrict__ bh,
    const float* __restrict__ bfv,
    const float* __restrict__ bdh,
    unsigned char* __restrict__ ws,
    float* __restrict__ out)
{
  const int bt  = blockIdx.x >> 5;    // batch tile 0..7
  const int ch  = blockIdx.x & 31;    // H chunk 0..31
  const int tid = threadIdx.x;
  const int wv  = tid >> 6;           // wave 0..3
  const int ln  = tid & 63;
  const int l15 = ln & 15;
  const int lq  = ln >> 4;

  _Float16*       hbuf = (_Float16*)(ws + OFF_HBUF);
  unsigned int*   cnt  = (unsigned int*)(ws + OFF_CNT);
  const float*    msum = (const float*)(ws + OFF_MSUM);
  const float*    bgq  = (const float*)(ws + OFF_BG);
  const f16x8*    WhP  = (const f16x8*)(ws + OFF_WH);
  const f16x8*    WfP  = (const f16x8*)(ws + OFF_WF);
  const f16x8*    WdP  = (const f16x8*)(ws + OFF_WD);
  const f16x8*    GBP  = (const f16x8*)(ws + OFF_GB);
  const _Float16* mbf  = (const _Float16*)(ws + OFF_MBF);
  const _Float16* dbf  = (const _Float16*)(ws + OFF_DBF);

  __shared__ __align__(16) _Float16 xcT[16][136];   // +8 pad keeps 16B align, breaks conflicts
  __shared__ __align__(16) _Float16 ccT[16][136];
  __shared__ float gbuf[4][16][16];
  __shared__ float cst[16][16];
  __shared__ float invms[256];
  __shared__ float bh_s[128], bf_s[128], bdh_s[16], bg_s[4][16];
  __shared__ float red[256];

  invms[tid] = 1.0f / (msum[tid] + 1e-5f);
  if (tid < 128) { bh_s[tid] = bh[tid]; bf_s[tid] = bfv[tid]; }
  if (tid < 16)  bdh_s[tid] = bdh[ch*16 + tid];
  if (tid < 64)  bg_s[tid>>4][tid&15] = bgq[(tid>>4)*512 + ch*16 + (tid&15)];
  ((float*)cst)[tid] = 0.0f;
  __syncthreads();

  // ---- persistent weight fragments in VGPRs ----
  f16x8 WhB[2][16], WfB[2][4], GB[24], WdB[4];
  #pragma unroll
  for (int i=0;i<2;i++)
    #pragma unroll
    for (int ks=0;ks<16;ks++)
      WhB[i][ks] = WhP[((2*wv+i)*16 + ks)*64 + ln];
  #pragma unroll
  for (int i=0;i<2;i++)
    #pragma unroll
    for (int ks=0;ks<4;ks++)
      WfB[i][ks] = WfP[((2*wv+i)*4 + ks)*64 + ln];
  #pragma unroll
  for (int ks=0;ks<24;ks++)
    GB[ks] = GBP[((ch*4 + wv)*24 + ks)*64 + ln];
  #pragma unroll
  for (int ks=0;ks<4;ks++)
    WdB[ks] = WdP[(ch*4 + ks)*64 + ln];

  float loss_acc = 0.0f;
  const int rowg = bt*16;

  #pragma unroll 1
  for (int t = 0; t < 256; ++t) {
    // ---- prefetch step inputs that don't depend on h (before the sync) ----
    float xnv[2][4], mmv[2][4];
    #pragma unroll
    for (int i=0;i<2;i++){
      int col = (2*wv+i)*16 + l15;
      #pragma unroll
      for (int r=0;r<4;r++){
        float dv = data[((rowg + lq*4 + r)*256 + t)*128 + col];
        bool ok = (dv == dv);
        xnv[i][r] = ok ? dv : 0.0f;
        mmv[i][r] = ok ? 1.0f : 0.0f;
      }
    }
    f16x8 mA[4];
    #pragma unroll
    for (int k=0;k<4;k++)
      mA[k] = *(const f16x8*)(mbf + ((size_t)(rowg+l15)*256 + t)*128 + k*32 + lq*8);
    f16x8 dA[4];
    if (wv == 0 && t < 255) {
      #pragma unroll
      for (int k=0;k<4;k++)
        dA[k] = *(const f16x8*)(dbf + ((size_t)(rowg+l15)*256 + (t+1))*128 + k*32 + lq*8);
    }

    // ---- wait for h(t) from the 32 producers of this batch tile ----
    if (t > 0) {
      if (tid == 0) {
        while (__hip_atomic_load(&cnt[(t-1)*8 + bt], __ATOMIC_RELAXED,
                                 __HIP_MEMORY_SCOPE_AGENT) < 32u) {
          __builtin_amdgcn_s_sleep(2);
        }
      }
      __syncthreads();
      __threadfence();   // acquire: invalidate stale L1/L2 before reading hbuf
    }

    // ---- h A-fragments (already gamma_h-scaled by producers) ----
    f16x8 hA[16];
    const _Float16* hb = hbuf + (size_t)(t&1)*65536 + (size_t)(rowg + l15)*512 + lq*8;
    #pragma unroll
    for (int ks=0;ks<16;ks++)
      hA[ks] = *(const f16x8*)(hb + ks*32);

    // ---- x_h = sigmoid(h @ Wh^T + bh); loss1; x_c ----
    float xhv[2][4];
    float numer = 0.0f;
    #pragma unroll
    for (int i=0;i<2;i++){
      f32x4 a = {0.f,0.f,0.f,0.f};
      #pragma unroll
      for (int ks=0;ks<16;ks++)
        a = __builtin_amdgcn_mfma_f32_16x16x32_f16(hA[ks], WhB[i][ks], a, 0,0,0);
      int col = (2*wv+i)*16 + l15;
      float bhc = bh_s[col];
      #pragma unroll
      for (int r=0;r<4;r++){
        float s = sigm(a[r] + bhc);
        xhv[i][r] = s;
        numer += fabsf(xnv[i][r] - s) * mmv[i][r];
        float xc = (mmv[i][r] > 0.f) ? xnv[i][r] : s;
        xcT[lq*4 + r][col] = (_Float16)xc;
      }
    }
    __syncthreads();

    // ---- z_h = sigmoid(x_c @ Wf_m^T + bf); loss2; c_c ----
    f16x8 xcA[4];
    #pragma unroll
    for (int k=0;k<4;k++)
      xcA[k] = *(const f16x8*)(&xcT[l15][k*32 + lq*8]);
    #pragma unroll
    for (int i=0;i<2;i++){
      f32x4 a = {0.f,0.f,0.f,0.f};
      #pragma unroll
      for (int ks=0;ks<4;ks++)
        a = __builtin_amdgcn_mfma_f32_16x16x32_f16(xcA[ks], WfB[i][ks], a, 0,0,0);
      int col = (2*wv+i)*16 + l15;
      float bfc = bf_s[col];
      #pragma unroll
      for (int r=0;r<4;r++){
        float z = sigm(a[r] + bfc);
        numer += fabsf(xnv[i][r] - z) * mmv[i][r];
        float chv = fabsf(0.5f*z + 0.5f*xhv[i][r]);
        float cc  = (mmv[i][r] > 0.f) ? xnv[i][r] : chv;
        int row = lq*4 + r;
        ccT[row][col] = (_Float16)cc;
        if (ch == 0) out[1 + ((size_t)(rowg+row)*256 + t)*128 + col] = cc;
      }
    }
    if (ch == 0) loss_acc += numer * invms[t];
    __syncthreads();

    // ---- gates chunk: [c_c,m] @ W_ih^T + h @ W_hh^T (wave wv owns gate wv of i,f,g,o) ----
    f16x8 ccA[4];
    #pragma unroll
    for (int k=0;k<4;k++)
      ccA[k] = *(const f16x8*)(&ccT[l15][k*32 + lq*8]);
    f32x4 g = {0.f,0.f,0.f,0.f};
    #pragma unroll
    for (int k=0;k<4;k++)  g = __builtin_amdgcn_mfma_f32_16x16x32_f16(ccA[k], GB[k],     g, 0,0,0);
    #pragma unroll
    for (int k=0;k<4;k++)  g = __builtin_amdgcn_mfma_f32_16x16x32_f16(mA[k],  GB[4+k],  g, 0,0,0);
    #pragma unroll
    for (int ks=0;ks<16;ks++) g = __builtin_amdgcn_mfma_f32_16x16x32_f16(hA[ks], GB[8+ks], g, 0,0,0);
    #pragma unroll
    for (int r=0;r<4;r++) gbuf[wv][lq*4 + r][l15] = g[r];
    __syncthreads();

    // ---- LSTM cell epilogue + gamma_h(t+1)-scaled h store (wave 0) ----
    if (wv == 0) {
      f32x4 ga = {0.f,0.f,0.f,0.f};
      if (t < 255) {
        #pragma unroll
        for (int k=0;k<4;k++)
          ga = __builtin_amdgcn_mfma_f32_16x16x32_f16(dA[k], WdB[k], ga, 0,0,0);
      }
      #pragma unroll
      for (int r=0;r<4;r++){
        int row = lq*4 + r;
        float ii = gbuf[0][row][l15] + bg_s[0][l15];
        float ff = gbuf[1][row][l15] + bg_s[1][l15];
        float gg = gbuf[2][row][l15] + bg_s[2][l15];
        float oo = gbuf[3][row][l15] + bg_s[3][l15];
        float co = cst[row][l15];
        float cn = sigm(ff)*co + sigm(ii)*tanh_(gg);
        cst[row][l15] = cn;
        if (t < 255) {
          float hn = sigm(oo)*tanh_(cn);
          float gh = __expf(-fmaxf(ga[r] + bdh_s[l15], 0.0f));
          hbuf[(size_t)((t+1)&1)*65536 + (size_t)(rowg+row)*512 + ch*16 + l15] =
              (_Float16)(hn * gh);
        }
      }
      if (t < 255) {
        __threadfence();   // release: drain h stores before signaling
        if (ln == 0)
          __hip_atomic_fetch_add(&cnt[t*8 + bt], 1u, __ATOMIC_RELEASE,
                                 __HIP_MEMORY_SCOPE_AGENT);
      }
    }
  }

  // ---- loss reduction (chunk-0 blocks only) ----
  if (ch == 0) {
    red[tid] = loss_acc;
    __syncthreads();
    if (tid == 0) {
      float s = 0.f;
      for (int i=0;i<256;i++) s += red[i];
      atomicAdd(out, 0.3f * s);
    }
  }
}

// ---------------- launch ----------------

extern "C" void kernel_launch(void* const* d_in, const int* in_sizes, int n_in,
                              void* d_out, int out_size, void* d_ws, size_t ws_size,
                              hipStream_t stream) {
  const float* data = (const float*)d_in[0];
  const float* W_ih = (const float*)d_in[1];
  const float* b_ih = (const float*)d_in[2];
  const float* W_hh = (const float*)d_in[3];
  const float* b_hh = (const float*)d_in[4];
  const float* Wdh  = (const float*)d_in[5];
  const float* bdh  = (const float*)d_in[6];
  // d_in[7] Wdx, d_in[8] bdx: dead code in reference forward
  const float* Wh   = (const float*)d_in[9];
  const float* bh   = (const float*)d_in[10];
  const float* Wf   = (const float*)d_in[11];
  const float* bf   = (const float*)d_in[12];
  // d_in[13] Wc, d_in[14] bc: dead code
  float* out = (float*)d_out;
  unsigned char* ws = (unsigned char*)d_ws;

  k_zero     <<<265,  256, 0, stream>>>((unsigned int*)d_ws, out);
  k_mask     <<<16384,256, 0, stream>>>(data, (_Float16*)(ws + OFF_MBF), (float*)(ws + OFF_MSUM));
  k_delta    <<<512,  64,  0, stream>>>(data, (_Float16*)(ws + OFF_DBF));
  k_pack_wh  <<<256,  256, 0, stream>>>(Wh,  (_Float16*)(ws + OFF_WH));
  k_pack_wf  <<<64,   256, 0, stream>>>(Wf,  (_Float16*)(ws + OFF_WF));
  k_pack_wd  <<<256,  256, 0, stream>>>(Wdh, (_Float16*)(ws + OFF_WD));
  k_pack_gb  <<<6144, 256, 0, stream>>>(W_ih, W_hh, (_Float16*)(ws + OFF_GB));
  k_pack_bias<<<8,    256, 0, stream>>>(b_ih, b_hh, (float*)(ws + OFF_BG));
  brits_main <<<256,  256, 0, stream>>>(data, bh, bf, bdh, ws, out);
}

// Round 3
// 2299.206 us; speedup vs baseline: 4.3902x; 4.3902x over previous
//
#include <hip/hip_runtime.h>

// BRITS-style recurrent imputation on MI355X.
// Partition: 256 blocks = 8 batch-tiles(16 rows) x 32 H-chunks(16 H each).
// Weights pre-packed to f16 MFMA B-fragments, persistent in VGPRs.
// R3: workspace shrunk to ~11.7 MB (R2's 20.75 MB overran ws_size into the
//     harness's pristine-input copy -> deterministic warm-launch corruption).
//     mA mask fragments now built on the fly from data (mbf buffer dropped).
//     Compiler fences around the h-handoff store/flag sequence.

#define B_ 128
#define T_ 256
#define D_ 128
#define H_ 512

typedef _Float16 f16x8 __attribute__((ext_vector_type(8)));
typedef float    f32x4 __attribute__((ext_vector_type(4)));

// ---- workspace layout (bytes), total 12,231,680 (< R1-proven 20,497,408) ----
#define OFF_HBUF   0u          // f16 [2][128][512]        262144
#define OFF_CNT    262144u     // uint [8][256] @64B       131072
#define OFF_MSUM   393216u     // float [256]              1024
#define OFF_BG     394240u     // float [2048]             8192
#define OFF_WH     402432u     // f16 [8][16][64][8]       131072
#define OFF_WF     533504u     // f16 [8][4][64][8]        32768
#define OFF_WD     566272u     // f16 [32][4][64][8]       131072
#define OFF_GB     697344u     // f16 [32][4][24][64][8]   3145728
#define OFF_DBF    3843072u    // f16 [128][256][128]      8388608

__device__ __forceinline__ float sigm(float x)  { return __fdividef(1.0f, 1.0f + __expf(-x)); }
__device__ __forceinline__ float tanh_(float x) { return 1.0f - __fdividef(2.0f, __expf(2.0f*x) + 1.0f); }

// ---------------- pre-kernels ----------------

__global__ void k_zero(unsigned int* __restrict__ wsu, float* __restrict__ out){
  int id = blockIdx.x*256 + threadIdx.x;
  if (id < 98560) wsu[id] = 0u;     // hbuf + cnt + msum
  if (id == 0) out[0] = 0.0f;
}

// msum[t] only (masks derived on the fly in brits_main)
__global__ void k_mask(const float* __restrict__ data, float* __restrict__ msum){
  int idx = blockIdx.x*256 + threadIdx.x;     // < 128*256*128
  float v = data[idx];
  bool m = (v == v);
  unsigned long long bal = __ballot(m);       // 64 lanes share one (b,t) row half
  if ((threadIdx.x & 63) == 0) {
    int t = (idx >> 7) & 255;
    atomicAdd(&msum[t], (float)__popcll(bal));
  }
}

// delta_calc: per (b,t) sequential scan over d (exact reference semantics)
__global__ void k_delta(const float* __restrict__ data, _Float16* __restrict__ dbf){
  int gid = blockIdx.x*64 + threadIdx.x;      // 32768 = B*T
  int b = gid >> 8, t = gid & 255;
  _Float16* orow = dbf + (size_t)(b*256 + t)*128;
  if (t == 0) {
    f16x8 z;
    #pragma unroll
    for (int i=0;i<8;i++) z[i] = (_Float16)0.0f;
    #pragma unroll
    for (int k=0;k<16;k++) ((f16x8*)orow)[k] = z;
    return;
  }
  const float* rp = data + (size_t)(b*256 + (t-1))*128;
  const float* rt = data + (size_t)(b*256 + t)*128;
  unsigned long long mp0=0, mp1=0, mt0=0, mt1=0;
  for (int d=0; d<64; ++d) {
    if (rp[d]==rp[d])       mp0 |= (1ull<<d);
    if (rp[64+d]==rp[64+d]) mp1 |= (1ull<<d);
    if (rt[d]==rt[d])       mt0 |= (1ull<<d);
    if (rt[64+d]==rt[64+d]) mt1 |= (1ull<<d);
  }
  float carry = 0.0f;
  for (int g=0; g<16; ++g) {
    f16x8 v;
    #pragma unroll
    for (int j=0; j<8; ++j) {
      int d = g*8 + j;
      bool prevm = (d<64)   ? ((mp0>>d)&1ull)       : ((mp1>>(d-64))&1ull);
      int dm1 = (d-1)&127;
      bool leftm = (dm1<64) ? ((mt0>>dm1)&1ull)     : ((mt1>>(dm1-64))&1ull);
      float val = (!prevm) ? (carry+1.0f) : (leftm ? 1.0f : 0.0f);
      carry = val;
      v[j] = (_Float16)val;
    }
    ((f16x8*)orow)[g] = v;
  }
}

// Weight pre-pack into MFMA B-fragment order: [..][ks][lane][8], B[k][n]=W[n][k],
// n = lane&15, k = ks*32 + (lane>>4)*8 + j.
__global__ void k_pack_wh(const float* __restrict__ Wh, _Float16* __restrict__ dst){
  int id = blockIdx.x*256 + threadIdx.x;      // 65536 = [8][16][64][8]
  int j = id & 7, l = (id>>3)&63, ks = (id>>9)&15, nt = id>>13;
  int row = nt*16 + (l&15);
  int k   = ks*32 + ((l>>4)&3)*8 + j;
  dst[id] = (_Float16)Wh[row*512 + k];
}
__global__ void k_pack_wf(const float* __restrict__ Wf, _Float16* __restrict__ dst){
  int id = blockIdx.x*256 + threadIdx.x;      // 16384 = [8][4][64][8]
  int j = id & 7, l = (id>>3)&63, ks = (id>>9)&3, nt = id>>11;
  int row = nt*16 + (l&15);
  int k   = ks*32 + ((l>>4)&3)*8 + j;
  float v = (row == k) ? 0.0f : Wf[row*128 + k];   // off-diagonal mask
  dst[id] = (_Float16)v;
}
__global__ void k_pack_wd(const float* __restrict__ Wdh, _Float16* __restrict__ dst){
  int id = blockIdx.x*256 + threadIdx.x;      // 65536 = [32][4][64][8]
  int j = id & 7, l = (id>>3)&63, ks = (id>>9)&3, c = id>>11;
  int row = c*16 + (l&15);
  int k   = ks*32 + ((l>>4)&3)*8 + j;
  dst[id] = (_Float16)Wdh[row*128 + k];
}
__global__ void k_pack_gb(const float* __restrict__ W_ih, const float* __restrict__ W_hh,
                          _Float16* __restrict__ dst){
  int id = blockIdx.x*256 + threadIdx.x;      // 1572864 = [32][4][24][64][8]
  int j = id & 7, l = (id>>3)&63;
  int f = id>>9;
  int ks = f % 24; f /= 24;
  int g = f & 3, c = f >> 2;
  int rn = g*512 + c*16 + (l&15);
  int k  = ks*32 + ((l>>4)&3)*8 + j;          // inp K: [0,256)=[c_c,m], [256,768)=h
  float v = (k < 256) ? W_ih[rn*256 + k] : W_hh[rn*512 + (k-256)];
  dst[id] = (_Float16)v;
}
__global__ void k_pack_bias(const float* __restrict__ b_ih, const float* __restrict__ b_hh,
                            float* __restrict__ dst){
  int id = blockIdx.x*256 + threadIdx.x;      // 2048
  dst[id] = b_ih[id] + b_hh[id];
}

// ---------------- main persistent kernel ----------------
// grid 256 blocks (8 batch-tiles x 32 chunks), 256 threads (4 waves, 1/SIMD).

__global__ __launch_bounds__(256, 1) void brits_main(
    const float* __restrict__ data,
    const float* __restrict__ bh,
    const float* __restrict__ bfv,
    const float* __restrict__ bdh,
    unsigned char* __restrict__ ws,
    float* __restrict__ out)
{
  const int bt  = blockIdx.x >> 5;    // batch tile 0..7
  const int ch  = blockIdx.x & 31;    // H chunk 0..31
  const int tid = threadIdx.x;
  const int wv  = tid >> 6;           // wave 0..3
  const int ln  = tid & 63;
  const int l15 = ln & 15;
  const int lq  = ln >> 4;

  _Float16*       hbuf = (_Float16*)(ws + OFF_HBUF);
  unsigned int*   cnt  = (unsigned int*)(ws + OFF_CNT);
  const float*    msum = (const float*)(ws + OFF_MSUM);
  const float*    bgq  = (const float*)(ws + OFF_BG);
  const f16x8*    WhP  = (const f16x8*)(ws + OFF_WH);
  const f16x8*    WfP  = (const f16x8*)(ws + OFF_WF);
  const f16x8*    WdP  = (const f16x8*)(ws + OFF_WD);
  const f16x8*    GBP  = (const f16x8*)(ws + OFF_GB);
  const _Float16* dbf  = (const _Float16*)(ws + OFF_DBF);

  __shared__ __align__(16) _Float16 xcT[16][136];
  __shared__ __align__(16) _Float16 ccT[16][136];
  __shared__ __align__(8)  _Float16 hstg[16][16];   // h staging for 8B bypass stores
  __shared__ float gbuf[4][16][16];
  __shared__ float cst[16][16];
  __shared__ float invms[256];
  __shared__ float bh_s[128], bf_s[128], bdh_s[16], bg_s[4][16];
  __shared__ float red[256];

  invms[tid] = 1.0f / (msum[tid] + 1e-5f);
  if (tid < 128) { bh_s[tid] = bh[tid]; bf_s[tid] = bfv[tid]; }
  if (tid < 16)  bdh_s[tid] = bdh[ch*16 + tid];
  if (tid < 64)  bg_s[tid>>4][tid&15] = bgq[(tid>>4)*512 + ch*16 + (tid&15)];
  ((float*)cst)[tid] = 0.0f;
  __syncthreads();

  // ---- persistent weight fragments in VGPRs ----
  f16x8 WhB[2][16], WfB[2][4], GB[24], WdB[4];
  #pragma unroll
  for (int i=0;i<2;i++)
    #pragma unroll
    for (int ks=0;ks<16;ks++)
      WhB[i][ks] = WhP[((2*wv+i)*16 + ks)*64 + ln];
  #pragma unroll
  for (int i=0;i<2;i++)
    #pragma unroll
    for (int ks=0;ks<4;ks++)
      WfB[i][ks] = WfP[((2*wv+i)*4 + ks)*64 + ln];
  #pragma unroll
  for (int ks=0;ks<24;ks++)
    GB[ks] = GBP[((ch*4 + wv)*24 + ks)*64 + ln];
  #pragma unroll
  for (int ks=0;ks<4;ks++)
    WdB[ks] = WdP[(ch*4 + ks)*64 + ln];

  float loss_acc = 0.0f;
  const int rowg = bt*16;

  #pragma unroll 1
  for (int t = 0; t < 256; ++t) {
    // ---- prefetch step inputs that don't depend on h (before the sync) ----
    float xnv[2][4], mmv[2][4];
    #pragma unroll
    for (int i=0;i<2;i++){
      int col = (2*wv+i)*16 + l15;
      #pragma unroll
      for (int r=0;r<4;r++){
        float dv = data[((rowg + lq*4 + r)*256 + t)*128 + col];
        bool ok = (dv == dv);
        xnv[i][r] = ok ? dv : 0.0f;
        mmv[i][r] = ok ? 1.0f : 0.0f;
      }
    }
    // mask A-fragments on the fly: element j of mA[k] = mask(b=rowg+l15, d=k*32+lq*8+j)
    f16x8 mA[4];
    {
      const float* mrow = data + ((size_t)(rowg + l15)*256 + t)*128 + lq*8;
      #pragma unroll
      for (int k=0;k<4;k++){
        float4 a0 = *(const float4*)(mrow + k*32);
        float4 a1 = *(const float4*)(mrow + k*32 + 4);
        f16x8 mv;
        mv[0] = (a0.x==a0.x)?(_Float16)1.0f:(_Float16)0.0f;
        mv[1] = (a0.y==a0.y)?(_Float16)1.0f:(_Float16)0.0f;
        mv[2] = (a0.z==a0.z)?(_Float16)1.0f:(_Float16)0.0f;
        mv[3] = (a0.w==a0.w)?(_Float16)1.0f:(_Float16)0.0f;
        mv[4] = (a1.x==a1.x)?(_Float16)1.0f:(_Float16)0.0f;
        mv[5] = (a1.y==a1.y)?(_Float16)1.0f:(_Float16)0.0f;
        mv[6] = (a1.z==a1.z)?(_Float16)1.0f:(_Float16)0.0f;
        mv[7] = (a1.w==a1.w)?(_Float16)1.0f:(_Float16)0.0f;
        mA[k] = mv;
      }
    }
    f16x8 dA[4];
    if (wv == 0 && t < 255) {
      #pragma unroll
      for (int k=0;k<4;k++)
        dA[k] = *(const f16x8*)(dbf + ((size_t)(rowg+l15)*256 + (t+1))*128 + k*32 + lq*8);
    }

    // ---- wait for h(t) from the 32 producers of this batch tile ----
    if (t > 0) {
      if (tid == 0) {
        const unsigned int* slot = cnt + (((bt<<8) + (t-1)) << 4);
        while (__hip_atomic_load(slot, __ATOMIC_RELAXED,
                                 __HIP_MEMORY_SCOPE_AGENT) < 32u) {
          __builtin_amdgcn_s_sleep(1);
        }
      }
      __syncthreads();
      // no HW fence needed: h is read via cache-bypassing atomic loads
    }

    // ---- h A-fragments via 8B bypassing atomic loads (fresh from IC) ----
    f16x8 hA[16];
    const _Float16* hb = hbuf + (size_t)(t&1)*65536 + (size_t)(rowg + l15)*512 + lq*8;
    #pragma unroll
    for (int ks=0;ks<16;ks++) {
      union { unsigned long long u[2]; f16x8 v; } cv;
      cv.u[0] = __hip_atomic_load((const unsigned long long*)(hb + ks*32),
                                  __ATOMIC_RELAXED, __HIP_MEMORY_SCOPE_AGENT);
      cv.u[1] = __hip_atomic_load((const unsigned long long*)(hb + ks*32 + 4),
                                  __ATOMIC_RELAXED, __HIP_MEMORY_SCOPE_AGENT);
      hA[ks] = cv.v;
    }

    // ---- x_h = sigmoid(h @ Wh^T + bh); loss1; x_c ----
    float xhv[2][4];
    float numer = 0.0f;
    #pragma unroll
    for (int i=0;i<2;i++){
      f32x4 a = {0.f,0.f,0.f,0.f};
      #pragma unroll
      for (int ks=0;ks<16;ks++)
        a = __builtin_amdgcn_mfma_f32_16x16x32_f16(hA[ks], WhB[i][ks], a, 0,0,0);
      int col = (2*wv+i)*16 + l15;
      float bhc = bh_s[col];
      #pragma unroll
      for (int r=0;r<4;r++){
        float s = sigm(a[r] + bhc);
        xhv[i][r] = s;
        numer += fabsf(xnv[i][r] - s) * mmv[i][r];
        float xc = (mmv[i][r] > 0.f) ? xnv[i][r] : s;
        xcT[lq*4 + r][col] = (_Float16)xc;
      }
    }
    __syncthreads();

    // ---- z_h = sigmoid(x_c @ Wf_m^T + bf); loss2; c_c ----
    f16x8 xcA[4];
    #pragma unroll
    for (int k=0;k<4;k++)
      xcA[k] = *(const f16x8*)(&xcT[l15][k*32 + lq*8]);
    #pragma unroll
    for (int i=0;i<2;i++){
      f32x4 a = {0.f,0.f,0.f,0.f};
      #pragma unroll
      for (int ks=0;ks<4;ks++)
        a = __builtin_amdgcn_mfma_f32_16x16x32_f16(xcA[ks], WfB[i][ks], a, 0,0,0);
      int col = (2*wv+i)*16 + l15;
      float bfc = bf_s[col];
      #pragma unroll
      for (int r=0;r<4;r++){
        float z = sigm(a[r] + bfc);
        numer += fabsf(xnv[i][r] - z) * mmv[i][r];
        float chv = fabsf(0.5f*z + 0.5f*xhv[i][r]);
        float cc  = (mmv[i][r] > 0.f) ? xnv[i][r] : chv;
        int row = lq*4 + r;
        ccT[row][col] = (_Float16)cc;
        if (ch == 0) out[1 + ((size_t)(rowg+row)*256 + t)*128 + col] = cc;
      }
    }
    if (ch == 0) loss_acc += numer * invms[t];
    __syncthreads();

    // ---- gates chunk: [c_c,m] @ W_ih^T + h @ W_hh^T (wave wv owns gate wv) ----
    f16x8 ccA[4];
    #pragma unroll
    for (int k=0;k<4;k++)
      ccA[k] = *(const f16x8*)(&ccT[l15][k*32 + lq*8]);
    f32x4 g = {0.f,0.f,0.f,0.f};
    #pragma unroll
    for (int k=0;k<4;k++)  g = __builtin_amdgcn_mfma_f32_16x16x32_f16(ccA[k], GB[k],     g, 0,0,0);
    #pragma unroll
    for (int k=0;k<4;k++)  g = __builtin_amdgcn_mfma_f32_16x16x32_f16(mA[k],  GB[4+k],  g, 0,0,0);
    #pragma unroll
    for (int ks=0;ks<16;ks++) g = __builtin_amdgcn_mfma_f32_16x16x32_f16(hA[ks], GB[8+ks], g, 0,0,0);
    #pragma unroll
    for (int r=0;r<4;r++) gbuf[wv][lq*4 + r][l15] = g[r];
    __syncthreads();

    // ---- LSTM cell epilogue + gamma_h(t+1)-scaled h store (wave 0) ----
    if (wv == 0) {
      f32x4 ga = {0.f,0.f,0.f,0.f};
      if (t < 255) {
        #pragma unroll
        for (int k=0;k<4;k++)
          ga = __builtin_amdgcn_mfma_f32_16x16x32_f16(dA[k], WdB[k], ga, 0,0,0);
      }
      #pragma unroll
      for (int r=0;r<4;r++){
        int row = lq*4 + r;
        float ii = gbuf[0][row][l15] + bg_s[0][l15];
        float ff = gbuf[1][row][l15] + bg_s[1][l15];
        float gg = gbuf[2][row][l15] + bg_s[2][l15];
        float oo = gbuf[3][row][l15] + bg_s[3][l15];
        float co = cst[row][l15];
        float cn = sigm(ff)*co + sigm(ii)*tanh_(gg);
        cst[row][l15] = cn;
        if (t < 255) {
          float hn = sigm(oo)*tanh_(cn);
          float gh = __expf(-fmaxf(ga[r] + bdh_s[l15], 0.0f));
          hstg[row][l15] = (_Float16)(hn * gh);
        }
      }
      if (t < 255) {
        // compiler barrier: hstg f16 writes must precede the u64 re-read
        __asm__ __volatile__("" ::: "memory");
        // 8B cache-bypassing stores straight to the coherence point
        int row2 = ln >> 2, c4 = (ln & 3) * 4;
        unsigned long long v = *(const unsigned long long*)&hstg[row2][c4];
        __hip_atomic_store(
            (unsigned long long*)(hbuf + (size_t)((t+1)&1)*65536
                                  + (size_t)(rowg + row2)*512 + ch*16 + c4),
            v, __ATOMIC_RELAXED, __HIP_MEMORY_SCOPE_AGENT);
        __atomic_signal_fence(__ATOMIC_SEQ_CST);
        __builtin_amdgcn_s_waitcnt(0);   // stores complete => globally visible
        __atomic_signal_fence(__ATOMIC_SEQ_CST);
        if (ln == 0)
          __hip_atomic_fetch_add(cnt + (((bt<<8) + t) << 4), 1u,
                                 __ATOMIC_RELAXED, __HIP_MEMORY_SCOPE_AGENT);
      }
    }
  }

  // ---- loss reduction (chunk-0 blocks only) ----
  if (ch == 0) {
    red[tid] = loss_acc;
    __syncthreads();
    if (tid == 0) {
      float s = 0.f;
      for (int i=0;i<256;i++) s += red[i];
      atomicAdd(out, 0.3f * s);
    }
  }
}

// ---------------- launch ----------------

extern "C" void kernel_launch(void* const* d_in, const int* in_sizes, int n_in,
                              void* d_out, int out_size, void* d_ws, size_t ws_size,
                              hipStream_t stream) {
  const float* data = (const float*)d_in[0];
  const float* W_ih = (const float*)d_in[1];
  const float* b_ih = (const float*)d_in[2];
  const float* W_hh = (const float*)d_in[3];
  const float* b_hh = (const float*)d_in[4];
  const float* Wdh  = (const float*)d_in[5];
  const float* bdh  = (const float*)d_in[6];
  // d_in[7] Wdx, d_in[8] bdx: dead code in reference forward
  const float* Wh   = (const float*)d_in[9];
  const float* bh   = (const float*)d_in[10];
  const float* Wf   = (const float*)d_in[11];
  const float* bf   = (const float*)d_in[12];
  // d_in[13] Wc, d_in[14] bc: dead code
  float* out = (float*)d_out;
  unsigned char* ws = (unsigned char*)d_ws;

  k_zero     <<<385,  256, 0, stream>>>((unsigned int*)d_ws, out);
  k_mask     <<<16384,256, 0, stream>>>(data, (float*)(ws + OFF_MSUM));
  k_delta    <<<512,  64,  0, stream>>>(data, (_Float16*)(ws + OFF_DBF));
  k_pack_wh  <<<256,  256, 0, stream>>>(Wh,  (_Float16*)(ws + OFF_WH));
  k_pack_wf  <<<64,   256, 0, stream>>>(Wf,  (_Float16*)(ws + OFF_WF));
  k_pack_wd  <<<256,  256, 0, stream>>>(Wdh, (_Float16*)(ws + OFF_WD));
  k_pack_gb  <<<6144, 256, 0, stream>>>(W_ih, W_hh, (_Float16*)(ws + OFF_GB));
  k_pack_bias<<<8,    256, 0, stream>>>(b_ih, b_hh, (float*)(ws + OFF_BG));
  brits_main <<<256,  256, 0, stream>>>(data, bh, bf, bdh, ws, out);
}